// Round 2
// baseline (620.935 us; speedup 1.0000x reference)
//
#include <hip/hip_runtime.h>
#include <hip/hip_bf16.h>
#include <stdint.h>

#define DIN   4096
#define DOUT  4096
#define MROWS 8192   // B*S = 4*2048

typedef __bf16 bf16_t;
typedef __attribute__((ext_vector_type(8))) __bf16 bf16x8;
typedef __attribute__((ext_vector_type(4))) float   f32x4;

__device__ __forceinline__ unsigned short f2bf(float f) {
    union { float f; unsigned u; } v; v.f = f;
    unsigned r = v.u + 0x7FFFu + ((v.u >> 16) & 1u);   // RNE
    return (unsigned short)(r >> 16);
}

// ---------------------------------------------------------------------------
// Kernel 1: Wt[n][k] = bf16( base_T[k][n] + c * (2*mask[k][n] - 1) )
// 64x64 tile; float4/int4 global loads, ushort4 global stores.
// ---------------------------------------------------------------------------
__global__ __launch_bounds__(256)
void build_wt(const float* __restrict__ baseT,
              const int*   __restrict__ mask,
              const float* __restrict__ coeff,
              unsigned short* __restrict__ Wt) {
    __shared__ float tile[64][68];          // 68*4=272B row stride, 16B-aligned
    const float c = coeff[0];
    const int t  = threadIdx.x;
    const int n0 = blockIdx.x * 64;
    const int k0 = blockIdx.y * 64;

    // phase 1: load 64(k) x 64(n) fp32, fuse sign-correction, stage in LDS
    const int kr = t >> 4;                  // 0..15
    const int nv = (t & 15) * 4;            // 0..60
#pragma unroll
    for (int i = 0; i < 4; ++i) {
        const int kl = i * 16 + kr;
        const size_t idx = (size_t)(k0 + kl) * DOUT + n0 + nv;
        float4 b4 = *(const float4*)(baseT + idx);
        int4   m4 = *(const int4*)(mask + idx);
        float4 v;
        v.x = b4.x + c * (float)(2 * m4.x - 1);
        v.y = b4.y + c * (float)(2 * m4.y - 1);
        v.z = b4.z + c * (float)(2 * m4.z - 1);
        v.w = b4.w + c * (float)(2 * m4.w - 1);
        *(float4*)&tile[kl][nv] = v;
    }
    __syncthreads();

    // phase 2: write transposed, 4 k per thread -> ushort4 (8B) stores
    const int nr = t >> 4;                  // 0..15
    const int kv = (t & 15) * 4;            // 0..60
#pragma unroll
    for (int j = 0; j < 4; ++j) {
        const int nl = j * 16 + nr;
        ushort4 o;
        o.x = f2bf(tile[kv + 0][nl]);
        o.y = f2bf(tile[kv + 1][nl]);
        o.z = f2bf(tile[kv + 2][nl]);
        o.w = f2bf(tile[kv + 3][nl]);
        *(ushort4*)(Wt + (size_t)(n0 + nl) * DIN + k0 + kv) = o;
    }
}

// ---------------------------------------------------------------------------
// Kernel 2: x fp32 -> bf16 bits, 16 elements/thread, 16B loads + 16B stores
// ---------------------------------------------------------------------------
__global__ __launch_bounds__(256)
void cvt_x(const float* __restrict__ x, unsigned short* __restrict__ xb) {
    const int i = blockIdx.x * 256 + threadIdx.x;
    const float4* xv = (const float4*)x;
    float4 a = xv[4 * i + 0];
    float4 b = xv[4 * i + 1];
    float4 c = xv[4 * i + 2];
    float4 d = xv[4 * i + 3];
    union { ushort4 s[2]; uint4 u; } p0, p1;
    p0.s[0] = make_ushort4(f2bf(a.x), f2bf(a.y), f2bf(a.z), f2bf(a.w));
    p0.s[1] = make_ushort4(f2bf(b.x), f2bf(b.y), f2bf(b.z), f2bf(b.w));
    p1.s[0] = make_ushort4(f2bf(c.x), f2bf(c.y), f2bf(c.z), f2bf(c.w));
    p1.s[1] = make_ushort4(f2bf(d.x), f2bf(d.y), f2bf(d.z), f2bf(d.w));
    uint4* ov = (uint4*)xb;
    ov[2 * i + 0] = p0.u;
    ov[2 * i + 1] = p1.u;
}

// ---------------------------------------------------------------------------
// Kernel 3: out[m][n] = sum_k X[m][k] * Wt[n][k]   (bf16 in, fp32 out)
// m97 structure + XOR bank swizzle applied on the GLOBAL side of the
// global_load_lds staging (LDS dest is fixed wave-uniform+lane*16, so we
// permute which 16B global chunk each lane fetches instead):
//   chunk (row,kc) lives at LDS position (row, kc ^ ((row>>1)&3)).
// Fragment reads then hit all 32 banks across 8 consecutive rows -> only
// free 2-way aliasing remains.
// ---------------------------------------------------------------------------
__global__ __launch_bounds__(256, 2)
void gemm_bt(const unsigned short* __restrict__ X,    // [MROWS][DIN] bf16 bits
             const unsigned short* __restrict__ Wt,   // [DOUT][DIN]  bf16 bits
             float* __restrict__ out) {               // [MROWS][DOUT] fp32
    __shared__ __align__(16) bf16_t sA[128 * 32];     // [m][32k] 8 KB
    __shared__ __align__(16) bf16_t sB[128 * 32];     // [n][32k] 8 KB

    const int tid  = threadIdx.x;
    const int lane = tid & 63;
    const int wv   = tid >> 6;        // 0..3
    const int bm   = blockIdx.x & 63; // 64 m-tiles (fast) -> L3 reuse of Wt
    const int bn   = blockIdx.x >> 6; // 32 n-tiles
    const int wm   = wv >> 1;         // 0..1
    const int wn   = wv & 1;          // 0..1

    // ---- staging: lane l of wave w writes LDS position (row0, l&3).
    //      The data fetched for that position is global chunk (l&3)^((row0>>1)&3).
    const int row0 = wv * 32 + (lane >> 2);            // rows row0 and row0+16
    const int kcg  = (lane & 3) ^ ((row0 >> 1) & 3);   // swizzled source chunk
    const int kcol = kcg * 8;                          // element offset in k
    const unsigned short* gA0 = X  + (size_t)(bm * 128 + row0) * DIN + kcol;
    const unsigned short* gA1 = gA0 + 16 * DIN;        // (row0+16)>>1 &3 unchanged
    const unsigned short* gB0 = Wt + (size_t)(bn * 128 + row0) * DIN + kcol;
    const unsigned short* gB1 = gB0 + 16 * DIN;
    bf16_t* lA0 = sA + wv * 1024;
    bf16_t* lA1 = sA + wv * 1024 + 512;
    bf16_t* lB0 = sB + wv * 1024;
    bf16_t* lB1 = sB + wv * 1024 + 512;

    // ---- fragment read offsets; logical chunk lane>>4, unswizzle per row.
    //      (arow + mi*16)>>1 & 3 == arow>>1 & 3 (16 preserves the low bits)
    const int arow  = wm * 64 + (lane & 15);
    const int brow  = wn * 64 + (lane & 15);
    const int akoff = (((lane >> 4) ^ ((arow >> 1) & 3)) * 8);
    const int bkoff = (((lane >> 4) ^ ((brow >> 1) & 3)) * 8);

    f32x4 acc[4][4];
#pragma unroll
    for (int i = 0; i < 4; ++i)
#pragma unroll
        for (int j = 0; j < 4; ++j) acc[i][j] = (f32x4){0.f, 0.f, 0.f, 0.f};

    for (int kt = 0; kt < DIN / 32; ++kt) {
        __builtin_amdgcn_global_load_lds((const __attribute__((address_space(1))) void*)gA0,
                                         (__attribute__((address_space(3))) void*)lA0, 16, 0, 0);
        __builtin_amdgcn_global_load_lds((const __attribute__((address_space(1))) void*)gA1,
                                         (__attribute__((address_space(3))) void*)lA1, 16, 0, 0);
        __builtin_amdgcn_global_load_lds((const __attribute__((address_space(1))) void*)gB0,
                                         (__attribute__((address_space(3))) void*)lB0, 16, 0, 0);
        __builtin_amdgcn_global_load_lds((const __attribute__((address_space(1))) void*)gB1,
                                         (__attribute__((address_space(3))) void*)lB1, 16, 0, 0);
        gA0 += 32; gA1 += 32; gB0 += 32; gB1 += 32;
        __syncthreads();   // drains vmcnt(0): tiles resident

        bf16x8 af[4], bfr[4];
#pragma unroll
        for (int mi = 0; mi < 4; ++mi)
            af[mi] = *(const bf16x8*)&sA[(arow + mi * 16) * 32 + akoff];
#pragma unroll
        for (int ni = 0; ni < 4; ++ni)
            bfr[ni] = *(const bf16x8*)&sB[(brow + ni * 16) * 32 + bkoff];
#pragma unroll
        for (int mi = 0; mi < 4; ++mi)
#pragma unroll
            for (int ni = 0; ni < 4; ++ni)
                acc[mi][ni] = __builtin_amdgcn_mfma_f32_16x16x32_bf16(
                    af[mi], bfr[ni], acc[mi][ni], 0, 0, 0);
        __syncthreads();   // all waves done reading before next stage
    }

    // ---- epilogue: D row = (lane>>4)*4 + r, col = lane&15
    const int crow0 = bm * 128 + wm * 64 + (lane >> 4) * 4;
    const int ccol0 = bn * 128 + wn * 64 + (lane & 15);
#pragma unroll
    for (int mi = 0; mi < 4; ++mi)
#pragma unroll
        for (int ni = 0; ni < 4; ++ni)
#pragma unroll
            for (int r = 0; r < 4; ++r)
                out[(size_t)(crow0 + mi * 16 + r) * DOUT + (ccol0 + ni * 16)] =
                    acc[mi][ni][r];
}

extern "C" void kernel_launch(void* const* d_in, const int* in_sizes, int n_in,
                              void* d_out, int out_size, void* d_ws, size_t ws_size,
                              hipStream_t stream) {
    const float* x     = (const float*)d_in[0];
    const float* baseT = (const float*)d_in[1];
    const int*   mask  = (const int*)d_in[2];
    const float* coeff = (const float*)d_in[3];

    unsigned short* Wt = (unsigned short*)d_ws;                              // 32 MB
    unsigned short* Xb = (unsigned short*)((char*)d_ws + (size_t)DIN * DOUT * 2); // 64 MB
    float* out = (float*)d_out;

    build_wt<<<dim3(DOUT / 64, DIN / 64), 256, 0, stream>>>(baseT, mask, coeff, Wt);

    cvt_x<<<(MROWS * DIN / 16) / 256, 256, 0, stream>>>(x, Xb);

    gemm_bt<<<64 * 32, 256, 0, stream>>>(Xb, Wt, out);
}

// Round 3
// 558.607 us; speedup vs baseline: 1.1116x; 1.1116x over previous
//
#include <hip/hip_runtime.h>
#include <hip/hip_bf16.h>
#include <stdint.h>

#define DIN   4096
#define DOUT  4096
#define MROWS 8192   // B*S = 4*2048

typedef __bf16 bf16_t;
typedef __attribute__((ext_vector_type(8))) __bf16 bf16x8;
typedef __attribute__((ext_vector_type(4))) float   f32x4;

__device__ __forceinline__ unsigned short f2bf(float f) {
    union { float f; unsigned u; } v; v.f = f;
    unsigned r = v.u + 0x7FFFu + ((v.u >> 16) & 1u);   // RNE
    return (unsigned short)(r >> 16);
}

// ---------------------------------------------------------------------------
// Kernel 1: Wt[n][k] = bf16( base_T[k][n] + c * (2*mask[k][n] - 1) )
// ---------------------------------------------------------------------------
__global__ __launch_bounds__(256)
void build_wt(const float* __restrict__ baseT,
              const int*   __restrict__ mask,
              const float* __restrict__ coeff,
              unsigned short* __restrict__ Wt) {
    __shared__ float tile[64][68];
    const float c = coeff[0];
    const int t  = threadIdx.x;
    const int n0 = blockIdx.x * 64;
    const int k0 = blockIdx.y * 64;

    const int kr = t >> 4;
    const int nv = (t & 15) * 4;
#pragma unroll
    for (int i = 0; i < 4; ++i) {
        const int kl = i * 16 + kr;
        const size_t idx = (size_t)(k0 + kl) * DOUT + n0 + nv;
        float4 b4 = *(const float4*)(baseT + idx);
        int4   m4 = *(const int4*)(mask + idx);
        float4 v;
        v.x = b4.x + c * (float)(2 * m4.x - 1);
        v.y = b4.y + c * (float)(2 * m4.y - 1);
        v.z = b4.z + c * (float)(2 * m4.z - 1);
        v.w = b4.w + c * (float)(2 * m4.w - 1);
        *(float4*)&tile[kl][nv] = v;
    }
    __syncthreads();

    const int nr = t >> 4;
    const int kv = (t & 15) * 4;
#pragma unroll
    for (int j = 0; j < 4; ++j) {
        const int nl = j * 16 + nr;
        ushort4 o;
        o.x = f2bf(tile[kv + 0][nl]);
        o.y = f2bf(tile[kv + 1][nl]);
        o.z = f2bf(tile[kv + 2][nl]);
        o.w = f2bf(tile[kv + 3][nl]);
        *(ushort4*)(Wt + (size_t)(n0 + nl) * DIN + k0 + kv) = o;
    }
}

// ---------------------------------------------------------------------------
// Kernel 2: x fp32 -> bf16 bits, 16 elem/thread
// ---------------------------------------------------------------------------
__global__ __launch_bounds__(256)
void cvt_x(const float* __restrict__ x, unsigned short* __restrict__ xb) {
    const int i = blockIdx.x * 256 + threadIdx.x;
    const float4* xv = (const float4*)x;
    float4 a = xv[4 * i + 0];
    float4 b = xv[4 * i + 1];
    float4 c = xv[4 * i + 2];
    float4 d = xv[4 * i + 3];
    union { ushort4 s[2]; uint4 u; } p0, p1;
    p0.s[0] = make_ushort4(f2bf(a.x), f2bf(a.y), f2bf(a.z), f2bf(a.w));
    p0.s[1] = make_ushort4(f2bf(b.x), f2bf(b.y), f2bf(b.z), f2bf(b.w));
    p1.s[0] = make_ushort4(f2bf(c.x), f2bf(c.y), f2bf(c.z), f2bf(c.w));
    p1.s[1] = make_ushort4(f2bf(d.x), f2bf(d.y), f2bf(d.z), f2bf(d.w));
    uint4* ov = (uint4*)xb;
    ov[2 * i + 0] = p0.u;
    ov[2 * i + 1] = p1.u;
}

// ---------------------------------------------------------------------------
// Kernel 3: out[m][n] = sum_k X[m][k] * Wt[n][k]   (bf16 in, fp32 out)
// BK=64: 32 MFMAs + 16 ds_read_b128 per barrier pair, 64 K-iterations
// (halves barrier-drain count vs BK=32). LDS 32 KB.
// XOR swizzle (8 chunks/row): phys chunk p at row r holds global chunk
// p ^ (r&7) -> fragment reads cover all 32 banks per 8 rows (conflict-free).
// ---------------------------------------------------------------------------
__global__ __launch_bounds__(256, 2)
void gemm_bt(const unsigned short* __restrict__ X,    // [MROWS][DIN] bf16 bits
             const unsigned short* __restrict__ Wt,   // [DOUT][DIN]  bf16 bits
             float* __restrict__ out) {               // [MROWS][DOUT] fp32
    __shared__ __align__(16) bf16_t sA[128 * 64];     // [m][64k] 16 KB
    __shared__ __align__(16) bf16_t sB[128 * 64];     // [n][64k] 16 KB

    const int tid  = threadIdx.x;
    const int lane = tid & 63;
    const int wv   = tid >> 6;        // 0..3
    const int bm   = blockIdx.x & 63; // 64 m-tiles (fast) -> L3 reuse of Wt
    const int bn   = blockIdx.x >> 6; // 32 n-tiles
    const int wm   = wv >> 1;         // 0..1
    const int wn   = wv & 1;          // 0..1

    // ---- staging: wave w stages rows w*32..w*32+31 (4 loads of 8 rows).
    //      lane l -> row offset l>>3, phys chunk l&7; swizzled source chunk:
    const int row0  = wv * 32 + (lane >> 3);
    const int kcol  = ((lane & 7) ^ (lane >> 3)) * 8;   // chunk_log * 8
    const unsigned short* gA = X  + (size_t)(bm * 128 + row0) * DIN + kcol;
    const unsigned short* gB = Wt + (size_t)(bn * 128 + row0) * DIN + kcol;
    bf16_t* lA = sA + wv * 2048;      // wave region: 4 KB = 2048 elems
    bf16_t* lB = sB + wv * 2048;

    // ---- fragment read offsets (A: m=lane&15, k=(lane>>4)*8+j per kstep)
    //      row&7 == lane&7 for all fragment rows -> unswizzle with lane&7.
    const int arow  = wm * 64 + (lane & 15);
    const int brow  = wn * 64 + (lane & 15);
    const int koff0 = (((lane >> 4) + 0) ^ (lane & 7)) * 8;  // kstep 0
    const int koff1 = (((lane >> 4) + 4) ^ (lane & 7)) * 8;  // kstep 1

    f32x4 acc[4][4];
#pragma unroll
    for (int i = 0; i < 4; ++i)
#pragma unroll
        for (int j = 0; j < 4; ++j) acc[i][j] = (f32x4){0.f, 0.f, 0.f, 0.f};

    for (int kt = 0; kt < DIN / 64; ++kt) {
#pragma unroll
        for (int i = 0; i < 4; ++i)
            __builtin_amdgcn_global_load_lds(
                (const __attribute__((address_space(1))) void*)(gA + (size_t)i * 8 * DIN),
                (__attribute__((address_space(3))) void*)(lA + i * 512), 16, 0, 0);
#pragma unroll
        for (int i = 0; i < 4; ++i)
            __builtin_amdgcn_global_load_lds(
                (const __attribute__((address_space(1))) void*)(gB + (size_t)i * 8 * DIN),
                (__attribute__((address_space(3))) void*)(lB + i * 512), 16, 0, 0);
        gA += 64; gB += 64;
        __syncthreads();   // tiles resident

#pragma unroll
        for (int ks = 0; ks < 2; ++ks) {
            const int ko = ks ? koff1 : koff0;
            bf16x8 af[4], bfr[4];
#pragma unroll
            for (int mi = 0; mi < 4; ++mi)
                af[mi] = *(const bf16x8*)&sA[(arow + mi * 16) * 64 + ko];
#pragma unroll
            for (int ni = 0; ni < 4; ++ni)
                bfr[ni] = *(const bf16x8*)&sB[(brow + ni * 16) * 64 + ko];
#pragma unroll
            for (int mi = 0; mi < 4; ++mi)
#pragma unroll
                for (int ni = 0; ni < 4; ++ni)
                    acc[mi][ni] = __builtin_amdgcn_mfma_f32_16x16x32_bf16(
                        af[mi], bfr[ni], acc[mi][ni], 0, 0, 0);
        }
        __syncthreads();   // all waves done reading before next stage
    }

    // ---- epilogue: D row = (lane>>4)*4 + r, col = lane&15
    const int crow0 = bm * 128 + wm * 64 + (lane >> 4) * 4;
    const int ccol0 = bn * 128 + wn * 64 + (lane & 15);
#pragma unroll
    for (int mi = 0; mi < 4; ++mi)
#pragma unroll
        for (int ni = 0; ni < 4; ++ni)
#pragma unroll
            for (int r = 0; r < 4; ++r)
                out[(size_t)(crow0 + mi * 16 + r) * DOUT + (ccol0 + ni * 16)] =
                    acc[mi][ni][r];
}

extern "C" void kernel_launch(void* const* d_in, const int* in_sizes, int n_in,
                              void* d_out, int out_size, void* d_ws, size_t ws_size,
                              hipStream_t stream) {
    const float* x     = (const float*)d_in[0];
    const float* baseT = (const float*)d_in[1];
    const int*   mask  = (const int*)d_in[2];
    const float* coeff = (const float*)d_in[3];

    unsigned short* Wt = (unsigned short*)d_ws;                              // 32 MB
    unsigned short* Xb = (unsigned short*)((char*)d_ws + (size_t)DIN * DOUT * 2); // 64 MB
    float* out = (float*)d_out;

    build_wt<<<dim3(DOUT / 64, DIN / 64), 256, 0, stream>>>(baseT, mask, coeff, Wt);

    cvt_x<<<(MROWS * DIN / 16) / 256, 256, 0, stream>>>(x, Xb);

    gemm_bt<<<64 * 32, 256, 0, stream>>>(Xb, Wt, out);
}